// Round 1
// baseline (486.945 us; speedup 1.0000x reference)
//
#include <hip/hip_runtime.h>
#include <hip/hip_bf16.h>

#define NHEADS 8
#define DK 64
#define DV 64
#define CIN 512
#define PIX_PER_IMG 4096
#define NPIX 65536

typedef short bf16x8 __attribute__((ext_vector_type(8)));
typedef float f32x4 __attribute__((ext_vector_type(4)));

__device__ __forceinline__ float b2f(unsigned short u) {
  union { unsigned int i; float f; } v; v.i = ((unsigned int)u) << 16; return v.f;
}
__device__ __forceinline__ unsigned short f2b(float f) {
  union { float f; unsigned int i; } v; v.f = f;
  unsigned int x = v.i;
  return (unsigned short)((x + 0x7fffu + ((x >> 16) & 1u)) >> 16);
}
__device__ __forceinline__ void gload_lds16(const void* g, void* l) {
  __builtin_amdgcn_global_load_lds(
      (const __attribute__((address_space(1))) void*)g,
      (__attribute__((address_space(3))) void*)l, 16, 0, 0);
}

// ---------------- K1: pooled sums (partial) + x -> bf16 conversion ----------
__global__ void k_pool_convert(const float* __restrict__ x,
                               unsigned short* __restrict__ xb,
                               float* __restrict__ partial) {
  int blk = blockIdx.x;             // 1024 = 16 images * 64 chunks
  int b = blk >> 6, chunk = blk & 63;
  int t = threadIdx.x;              // 256
  size_t base = ((size_t)b * PIX_PER_IMG + (size_t)chunk * 64) * CIN;
  const float* xp = x + base;
  unsigned short* xbp = xb + base;
  float a0 = 0.f, a1 = 0.f;
  for (int p = 0; p < 64; ++p) {
    float v0 = xp[p * CIN + t];
    float v1 = xp[p * CIN + t + 256];
    a0 += v0; a1 += v1;
    xbp[p * CIN + t] = f2b(v0);
    xbp[p * CIN + t + 256] = f2b(v1);
  }
  partial[(size_t)blk * CIN + t] = a0;
  partial[(size_t)blk * CIN + t + 256] = a1;
}

// ---------------- K2a: xbar -> q -> P, s0  (one block per image) -----------
__global__ void k_qp(const float* __restrict__ partial,
                     const float* __restrict__ Wq, const float* __restrict__ bq,
                     const float* __restrict__ Wk, const float* __restrict__ bk,
                     float* __restrict__ P, float* __restrict__ s0) {
  __shared__ float xbar[CIN];
  __shared__ float qv[CIN];
  int b = blockIdx.x, t = threadIdx.x;
  for (int c = t; c < CIN; c += 256) {
    float s = 0.f;
    for (int ch = 0; ch < 64; ++ch) s += partial[((size_t)(b * 64 + ch)) * CIN + c];
    xbar[c] = s * (1.0f / 4096.0f);
  }
  __syncthreads();
  for (int j = t; j < CIN; j += 256) {
    float a = bq[j];
    for (int c = 0; c < CIN; ++c) a += xbar[c] * Wq[(size_t)c * CIN + j];
    qv[j] = a;
  }
  __syncthreads();
  for (int idx = t; idx < NHEADS * CIN; idx += 256) {
    int n = idx >> 9, c = idx & 511;
    float a = 0.f;
    const float* wr = Wk + (size_t)c * CIN + n * DK;
    const float* qr = qv + n * DK;
    for (int k = 0; k < DK; ++k) a += wr[k] * qr[k];
    P[((size_t)(b * NHEADS + n)) * CIN + c] = a;
  }
  if (t < NHEADS) {
    float a = 0.f;
    for (int k = 0; k < DK; ++k) a += qv[t * DK + k] * bk[t * DK + k];
    s0[b * NHEADS + t] = a;
  }
}

// ---------------- K2b: weight transposes -> bf16 ---------------------------
__global__ void k_prep_w(const float* __restrict__ Wv, const float* __restrict__ Wo,
                         unsigned short* __restrict__ WvT, unsigned short* __restrict__ WoT) {
  int idx = blockIdx.x * 256 + threadIdx.x;   // grid 1152 -> 294912
  if (idx < 262144) {
    int n = idx >> 9, c = idx & 511;          // WvT[n][c] = Wv[c][n]
    WvT[idx] = f2b(Wv[(size_t)c * 512 + n]);
  } else {
    int j = idx - 262144;                      // 32768: WoT[o][k] = Wo[k][o]
    int o = j >> 6, k = j & 63;
    WoT[j] = f2b(Wo[(size_t)k * 512 + o]);
  }
}

// ---------------- GEMM: A[M][K] bf16 (row-major), BT[N][K] bf16 ------------
// 128x128 tile, BK=64, 256 threads (2x2 waves of 64x64), 16x16x32 MFMA.
template <int KTILES, bool OUT_BF16>
__global__ void k_gemm(const unsigned short* __restrict__ A,
                       const unsigned short* __restrict__ BT,
                       const float* __restrict__ bias,
                       void* __restrict__ Cout) {
  __shared__ __align__(16) unsigned short As[128 * 64];
  __shared__ __align__(16) unsigned short Bs[128 * 64];
  const int t = threadIdx.x;
  const int wave = t >> 6, lane = t & 63;
  const int wr = wave >> 1, wc = wave & 1;
  const int m0 = blockIdx.y * 128, n0 = blockIdx.x * 128;
  const int K = KTILES * 64;

  f32x4 acc[4][4];
  for (int i = 0; i < 4; ++i)
    for (int j = 0; j < 4; ++j) acc[i][j] = (f32x4){0.f, 0.f, 0.f, 0.f};

  const int srow = wave * 32 + (lane >> 3);   // staging row within tile (+ j*8)
  const int scolb = (lane & 7) * 16;          // byte offset within 128B row

  for (int kt = 0; kt < KTILES; ++kt) {
    __syncthreads();
    const char* gA = (const char*)A + ((size_t)(m0 + srow) * K + kt * 64) * 2 + scolb;
    const char* gB = (const char*)BT + ((size_t)(n0 + srow) * K + kt * 64) * 2 + scolb;
    char* lA = (char*)As + wave * 4096;
    char* lB = (char*)Bs + wave * 4096;
#pragma unroll
    for (int j = 0; j < 4; ++j) {
      gload_lds16(gA + (size_t)j * 8 * K * 2, lA + j * 1024);
      gload_lds16(gB + (size_t)j * 8 * K * 2, lB + j * 1024);
    }
    __syncthreads();
#pragma unroll
    for (int s = 0; s < 2; ++s) {
      bf16x8 af[4], bg[4];
#pragma unroll
      for (int i = 0; i < 4; ++i) {
        int mrow = wr * 64 + i * 16 + (lane & 15);
        af[i] = *(const bf16x8*)((const char*)As + mrow * 128 + s * 64 + ((lane >> 4) * 16));
      }
#pragma unroll
      for (int j = 0; j < 4; ++j) {
        int nrow = wc * 64 + j * 16 + (lane & 15);
        bg[j] = *(const bf16x8*)((const char*)Bs + nrow * 128 + s * 64 + ((lane >> 4) * 16));
      }
#pragma unroll
      for (int i = 0; i < 4; ++i)
#pragma unroll
        for (int j = 0; j < 4; ++j)
          acc[i][j] = __builtin_amdgcn_mfma_f32_16x16x32_bf16(af[i], bg[j], acc[i][j], 0, 0, 0);
    }
  }
  // epilogue: C/D layout col = lane&15, row = (lane>>4)*4 + r
#pragma unroll
  for (int i = 0; i < 4; ++i)
#pragma unroll
    for (int j = 0; j < 4; ++j) {
      int mbase = m0 + wr * 64 + i * 16 + ((lane >> 4) * 4);
      int n = n0 + wc * 64 + j * 16 + (lane & 15);
      float bb = bias[n];
#pragma unroll
      for (int r = 0; r < 4; ++r) {
        float v = acc[i][j][r] + bb;
        if (OUT_BF16)
          ((unsigned short*)Cout)[(size_t)(mbase + r) * 512 + n] = f2b(v);
        else
          ((float*)Cout)[(size_t)(mbase + r) * 512 + n] = v;
      }
    }
}

// ---------------- K4: scores s[b,n,pix] = scale*(x.P + s0) -----------------
__global__ void k_scores(const unsigned short* __restrict__ xb,
                         const float* __restrict__ P, const float* __restrict__ s0,
                         float* __restrict__ s) {
  __shared__ float Pl[NHEADS * 516];
  __shared__ float s0l[NHEADS];
  int blk = blockIdx.x;   // 2048 = 16 images * 128 tiles of 32 pixels
  int b = blk >> 7, tile = blk & 127;
  int t = threadIdx.x;
  for (int idx = t; idx < NHEADS * CIN; idx += 256) {
    int n = idx >> 9, c = idx & 511;
    Pl[n * 516 + c] = P[((size_t)(b * NHEADS + n)) * CIN + c];
  }
  if (t < NHEADS) s0l[t] = s0[b * NHEADS + t];
  __syncthreads();
  int pl = t >> 3, n = t & 7;
  int pix = tile * 32 + pl;
  const uint4* xr = (const uint4*)(xb + ((size_t)b * PIX_PER_IMG + pix) * CIN);
  const float* Pr = Pl + n * 516;
  float acc = s0l[n];
  for (int cc = 0; cc < 64; ++cc) {
    uint4 u = xr[cc];
    int c = cc * 8;
    acc += b2f((unsigned short)(u.x & 0xffff)) * Pr[c + 0];
    acc += b2f((unsigned short)(u.x >> 16)) * Pr[c + 1];
    acc += b2f((unsigned short)(u.y & 0xffff)) * Pr[c + 2];
    acc += b2f((unsigned short)(u.y >> 16)) * Pr[c + 3];
    acc += b2f((unsigned short)(u.z & 0xffff)) * Pr[c + 4];
    acc += b2f((unsigned short)(u.z >> 16)) * Pr[c + 5];
    acc += b2f((unsigned short)(u.w & 0xffff)) * Pr[c + 6];
    acc += b2f((unsigned short)(u.w >> 16)) * Pr[c + 7];
  }
  s[((size_t)(b * NHEADS + n)) * PIX_PER_IMG + pix] = acc * 0.125f;
}

// ---------------- K5: row softmax (attn_h) + col softmax (attn_v) ----------
__global__ void k_softmax(const float* __restrict__ s,
                          float* __restrict__ ah, float* __restrict__ av) {
  __shared__ float st[4096];
  int bn = blockIdx.x, t = threadIdx.x;
  const float* sp = s + (size_t)bn * 4096;
  for (int i = t; i < 4096; i += 256) st[i] = sp[i];
  __syncthreads();
  if (t < 64) {
    int h = t;
    float m = -1e30f;
    for (int w = 0; w < 64; ++w) m = fmaxf(m, st[h * 64 + w]);
    float sum = 0.f;
    for (int w = 0; w < 64; ++w) sum += __expf(st[h * 64 + w] - m);
    float inv = 1.f / sum;
    for (int w = 0; w < 64; ++w)
      ah[(size_t)bn * 4096 + h * 64 + w] = __expf(st[h * 64 + w] - m) * inv;
  } else if (t < 128) {
    int w = t - 64;
    float m = -1e30f;
    for (int h = 0; h < 64; ++h) m = fmaxf(m, st[h * 64 + w]);
    float sum = 0.f;
    for (int h = 0; h < 64; ++h) sum += __expf(st[h * 64 + w] - m);
    float inv = 1.f / sum;
    for (int h = 0; h < 64; ++h)
      av[(size_t)bn * 4096 + h * 64 + w] = __expf(st[h * 64 + w] - m) * inv;
  }
}

// ---------------- K6: A_h[bn,h,v], A_v[bn,w,v] from V ----------------------
__global__ void __launch_bounds__(512) k_av(const unsigned short* __restrict__ V,
                                            const float* __restrict__ ahg,
                                            const float* __restrict__ avg,
                                            float* __restrict__ Ah,
                                            float* __restrict__ Av) {
  __shared__ float ah[4096], av[4096], red[512];
  int bn = blockIdx.x;    // 128
  int vh = blockIdx.y;    // 2 (v halves)
  int b = bn >> 3, n = bn & 7;
  int t = threadIdx.x;    // 512
  for (int i = t; i < 4096; i += 512) {
    ah[i] = ahg[(size_t)bn * 4096 + i];
    av[i] = avg[(size_t)bn * 4096 + i];
  }
  __syncthreads();
  int v = vh * 32 + (t & 31);
  int wg = t >> 5;        // 0..15
  float accv[4] = {0.f, 0.f, 0.f, 0.f};
  const unsigned short* Vb = V + (size_t)b * PIX_PER_IMG * 512 + n * 64 + v;
  for (int h = 0; h < 64; ++h) {
    float partial = 0.f;
#pragma unroll
    for (int j = 0; j < 4; ++j) {
      int w = wg + 16 * j;
      float val = b2f(Vb[(size_t)(h * 64 + w) * 512]);
      partial += ah[h * 64 + w] * val;
      accv[j] += av[h * 64 + w] * val;
    }
    red[t] = partial;
    __syncthreads();
    if (t < 32) {
      float sum = 0.f;
      for (int g = 0; g < 16; ++g) sum += red[t + 32 * g];
      Ah[((size_t)bn * 64 + h) * 64 + vh * 32 + t] = sum;
    }
    __syncthreads();
  }
#pragma unroll
  for (int j = 0; j < 4; ++j) {
    int w = wg + 16 * j;
    Av[((size_t)bn * 64 + w) * 64 + v] = accv[j];
  }
}

// ---------------- K7a: a[pix,v] = sum_n A_h*A_v -> bf16 --------------------
__global__ void k_combine(const float* __restrict__ Ah, const float* __restrict__ Av,
                          unsigned short* __restrict__ Af) {
  int t = threadIdx.x;
  int g = blockIdx.x * 4 + (t >> 6);
  int v = t & 63;
  int b = g >> 12;
  int rem = g & 4095;
  int h = rem >> 6, w = rem & 63;
  float a = 0.f;
#pragma unroll
  for (int n = 0; n < 8; ++n) {
    int bn = b * 8 + n;
    a += Ah[((size_t)bn * 64 + h) * 64 + v] * Av[((size_t)bn * 64 + w) * 64 + v];
  }
  Af[(size_t)g * 64 + v] = f2b(a);
}

extern "C" void kernel_launch(void* const* d_in, const int* in_sizes, int n_in,
                              void* d_out, int out_size, void* d_ws, size_t ws_size,
                              hipStream_t stream) {
  (void)in_sizes; (void)n_in; (void)out_size; (void)ws_size;
  const float* x = (const float*)d_in[0];
  const float* Wq = (const float*)d_in[1];
  const float* bq = (const float*)d_in[2];
  const float* Wk = (const float*)d_in[3];
  const float* bk = (const float*)d_in[4];
  const float* Wv = (const float*)d_in[5];
  const float* bv = (const float*)d_in[6];
  const float* Wo = (const float*)d_in[7];
  const float* bo = (const float*)d_in[8];
  float* out = (float*)d_out;

  char* ws = (char*)d_ws;
  // region0 (67,108,864 B): x_bf16 lives until k_scores; then reused.
  unsigned short* xb = (unsigned short*)(ws + 0);
  float* attn_h = (float*)(ws + 0);
  float* attn_v = (float*)(ws + 8388608);
  float* Ah = (float*)(ws + 16777216);
  float* Av = (float*)(ws + 18874368);
  unsigned short* Af = (unsigned short*)(ws + 20971520);
  unsigned short* V = (unsigned short*)(ws + 67108864);     // 67,108,864 B
  float* s = (float*)(ws + 134217728);                      // 8,388,608 B
  float* partial = (float*)(ws + 142606336);                // 2,097,152 B
  float* P = (float*)(ws + 144703488);                      // 262,144 B
  float* s0 = (float*)(ws + 144965632);                     // 512 B
  unsigned short* WvT = (unsigned short*)(ws + 144966144);  // 524,288 B
  unsigned short* WoT = (unsigned short*)(ws + 145490432);  // 65,536 B
  // total ws use ~145.6 MB

  k_pool_convert<<<1024, 256, 0, stream>>>(x, xb, partial);
  k_qp<<<16, 256, 0, stream>>>(partial, Wq, bq, Wk, bk, P, s0);
  k_prep_w<<<1152, 256, 0, stream>>>(Wv, Wo, WvT, WoT);
  k_gemm<8, true><<<dim3(4, 512), 256, 0, stream>>>(xb, WvT, bv, (void*)V);
  k_scores<<<2048, 256, 0, stream>>>(xb, P, s0, s);
  k_softmax<<<128, 256, 0, stream>>>(s, attn_h, attn_v);
  k_av<<<dim3(128, 2), 512, 0, stream>>>(V, attn_h, attn_v, Ah, Av);
  k_combine<<<16384, 256, 0, stream>>>(Ah, Av, Af);
  k_gemm<1, false><<<dim3(4, 512), 256, 0, stream>>>(Af, WoT, bo, (void*)out);
}

// Round 2
// 375.887 us; speedup vs baseline: 1.2955x; 1.2955x over previous
//
#include <hip/hip_runtime.h>
#include <hip/hip_bf16.h>

#define NHEADS 8
#define DK 64
#define DV 64
#define CIN 512
#define PIX_PER_IMG 4096
#define NPIX 65536

typedef short bf16x8 __attribute__((ext_vector_type(8)));
typedef float f32x4 __attribute__((ext_vector_type(4)));

__device__ __forceinline__ float b2f(unsigned int u) {
  union { unsigned int i; float f; } v; v.i = u << 16; return v.f;
}
__device__ __forceinline__ unsigned short f2b(float f) {
  union { float f; unsigned int i; } v; v.f = f;
  unsigned int x = v.i;
  return (unsigned short)((x + 0x7fffu + ((x >> 16) & 1u)) >> 16);
}
__device__ __forceinline__ void gload_lds16(const void* g, void* l) {
  __builtin_amdgcn_global_load_lds(
      (const __attribute__((address_space(1))) void*)g,
      (__attribute__((address_space(3))) void*)l, 16, 0, 0);
}

// ---------------- K1: pooled sums (partial) + x -> bf16 conversion ----------
__global__ void k_pool_convert(const float* __restrict__ x,
                               unsigned short* __restrict__ xb,
                               float* __restrict__ partial) {
  int blk = blockIdx.x;             // 1024 = 16 images * 64 chunks
  int b = blk >> 6, chunk = blk & 63;
  int t = threadIdx.x;              // 256
  size_t base = ((size_t)b * PIX_PER_IMG + (size_t)chunk * 64) * CIN;
  const float* xp = x + base;
  unsigned short* xbp = xb + base;
  float a0 = 0.f, a1 = 0.f;
  for (int p = 0; p < 64; ++p) {
    float v0 = xp[p * CIN + t];
    float v1 = xp[p * CIN + t + 256];
    a0 += v0; a1 += v1;
    xbp[p * CIN + t] = f2b(v0);
    xbp[p * CIN + t + 256] = f2b(v1);
  }
  partial[(size_t)blk * CIN + t] = a0;
  partial[(size_t)blk * CIN + t + 256] = a1;
}

// ---------------- K2a: partial -> xbar --------------------------------------
__global__ void k_xbar(const float* __restrict__ partial, float* __restrict__ xbar) {
  int gid = blockIdx.x * 256 + threadIdx.x;   // 8192 = 16*512
  int b = gid >> 9, c = gid & 511;
  float s = 0.f;
  for (int ch = 0; ch < 64; ++ch) s += partial[((size_t)(b * 64 + ch)) * CIN + c];
  xbar[gid] = s * (1.0f / 4096.0f);
}

// ---------------- K2b: q[b, n*64+jj] + s0[b,n] ------------------------------
__global__ void k_q(const float* __restrict__ xbar,
                    const float* __restrict__ Wq, const float* __restrict__ bq,
                    const float* __restrict__ bk,
                    float* __restrict__ qbuf, float* __restrict__ s0) {
  __shared__ float xs[CIN];
  __shared__ float red[256];
  __shared__ float qs[64];
  int b = blockIdx.x, n = blockIdx.y, t = threadIdx.x;
  xs[t] = xbar[b * CIN + t];
  xs[t + 256] = xbar[b * CIN + t + 256];
  __syncthreads();
  int jj = t & 63, part = t >> 6;
  float acc = 0.f;
  const float* wp = Wq + (size_t)(part * 128) * CIN + n * 64 + jj;
  for (int ci = 0; ci < 128; ++ci)
    acc += xs[part * 128 + ci] * wp[(size_t)ci * CIN];
  red[t] = acc;
  __syncthreads();
  if (t < 64) {
    float q = red[t] + red[t + 64] + red[t + 128] + red[t + 192] + bq[n * 64 + t];
    qbuf[b * CIN + n * 64 + t] = q;
    qs[t] = q * bk[n * 64 + t];
  }
  __syncthreads();
  if (t == 0) {
    float s = 0.f;
    for (int k = 0; k < 64; ++k) s += qs[k];
    s0[b * NHEADS + n] = s;
  }
}

// ---------------- K2c: P[b,n,c] = sum_k q[b,n,k]*Wk[c, n*64+k] --------------
__global__ void k_p(const float* __restrict__ qbuf, const float* __restrict__ Wk,
                    float* __restrict__ P) {
  __shared__ float wks[64 * 65];    // [k][c] padded
  __shared__ float qs2[16 * 64];    // [b][k]
  int n = blockIdx.x, cchunk = blockIdx.y, t = threadIdx.x;
  int c0 = cchunk * 64;
  for (int i = 0; i < 4; ++i) {
    int idx = i * 256 + t;          // 1024 = 16b*64k
    int bb = idx >> 6, k = idx & 63;
    qs2[idx] = qbuf[bb * CIN + n * 64 + k];
  }
  int k = t & 63;
  for (int i = 0; i < 16; ++i) {
    int r = i * 4 + (t >> 6);
    wks[k * 65 + r] = Wk[(size_t)(c0 + r) * CIN + n * 64 + k];
  }
  __syncthreads();
  int c = t & 63, bg = t >> 6;
  for (int b2 = bg * 4; b2 < bg * 4 + 4; ++b2) {
    float acc = 0.f;
    for (int kk = 0; kk < 64; ++kk) acc += qs2[b2 * 64 + kk] * wks[kk * 65 + c];
    P[((size_t)(b2 * NHEADS + n)) * CIN + c0 + c] = acc;
  }
}

// ---------------- K3: weight transposes -> bf16 -----------------------------
__global__ void k_prep_w(const float* __restrict__ Wv, const float* __restrict__ Wo,
                         unsigned short* __restrict__ WvT, unsigned short* __restrict__ WoT) {
  int idx = blockIdx.x * 256 + threadIdx.x;   // grid 1152 -> 294912
  if (idx < 262144) {
    int n = idx >> 9, c = idx & 511;          // WvT[n][c] = Wv[c][n]
    WvT[idx] = f2b(Wv[(size_t)c * 512 + n]);
  } else {
    int j = idx - 262144;                      // 32768: WoT[o][k] = Wo[k][o]
    int o = j >> 6, kk = j & 63;
    WoT[j] = f2b(Wo[(size_t)kk * 512 + o]);
  }
}

// ---------------- GEMM: A[M][K] bf16 (row-major), BT[N][K] bf16 -------------
// 128x128 tile, BK=64, 256 threads (2x2 waves of 64x64), 16x16x32 MFMA.
template <int KTILES, bool OUT_BF16>
__global__ void k_gemm(const unsigned short* __restrict__ A,
                       const unsigned short* __restrict__ BT,
                       const float* __restrict__ bias,
                       void* __restrict__ Cout) {
  __shared__ __align__(16) unsigned short As[128 * 64];
  __shared__ __align__(16) unsigned short Bs[128 * 64];
  const int t = threadIdx.x;
  const int wave = t >> 6, lane = t & 63;
  const int wr = wave >> 1, wc = wave & 1;
  const int m0 = blockIdx.y * 128, n0 = blockIdx.x * 128;
  const int K = KTILES * 64;

  f32x4 acc[4][4];
  for (int i = 0; i < 4; ++i)
    for (int j = 0; j < 4; ++j) acc[i][j] = (f32x4){0.f, 0.f, 0.f, 0.f};

  const int srow = wave * 32 + (lane >> 3);
  const int scolb = (lane & 7) * 16;

  for (int kt = 0; kt < KTILES; ++kt) {
    __syncthreads();
    const char* gA = (const char*)A + ((size_t)(m0 + srow) * K + kt * 64) * 2 + scolb;
    const char* gB = (const char*)BT + ((size_t)(n0 + srow) * K + kt * 64) * 2 + scolb;
    char* lA = (char*)As + wave * 4096;
    char* lB = (char*)Bs + wave * 4096;
#pragma unroll
    for (int j = 0; j < 4; ++j) {
      gload_lds16(gA + (size_t)j * 8 * K * 2, lA + j * 1024);
      gload_lds16(gB + (size_t)j * 8 * K * 2, lB + j * 1024);
    }
    __syncthreads();
#pragma unroll
    for (int s = 0; s < 2; ++s) {
      bf16x8 af[4], bg[4];
#pragma unroll
      for (int i = 0; i < 4; ++i) {
        int mrow = wr * 64 + i * 16 + (lane & 15);
        af[i] = *(const bf16x8*)((const char*)As + mrow * 128 + s * 64 + ((lane >> 4) * 16));
      }
#pragma unroll
      for (int j = 0; j < 4; ++j) {
        int nrow = wc * 64 + j * 16 + (lane & 15);
        bg[j] = *(const bf16x8*)((const char*)Bs + nrow * 128 + s * 64 + ((lane >> 4) * 16));
      }
#pragma unroll
      for (int i = 0; i < 4; ++i)
#pragma unroll
        for (int j = 0; j < 4; ++j)
          acc[i][j] = __builtin_amdgcn_mfma_f32_16x16x32_bf16(af[i], bg[j], acc[i][j], 0, 0, 0);
    }
  }
#pragma unroll
  for (int i = 0; i < 4; ++i)
#pragma unroll
    for (int j = 0; j < 4; ++j) {
      int mbase = m0 + wr * 64 + i * 16 + ((lane >> 4) * 4);
      int n = n0 + wc * 64 + j * 16 + (lane & 15);
      float bb = bias[n];
#pragma unroll
      for (int r = 0; r < 4; ++r) {
        float v = acc[i][j][r] + bb;
        if (OUT_BF16)
          ((unsigned short*)Cout)[(size_t)(mbase + r) * 512 + n] = f2b(v);
        else
          ((float*)Cout)[(size_t)(mbase + r) * 512 + n] = v;
      }
    }
}

// ---------------- K4: scores s[b,n,pix] = scale*(x.P + s0) ------------------
__global__ void k_scores(const unsigned short* __restrict__ xb,
                         const float* __restrict__ P, const float* __restrict__ s0,
                         float* __restrict__ s) {
  __shared__ float Pl[NHEADS * 516];
  __shared__ float s0l[NHEADS];
  int blk = blockIdx.x;   // 2048 = 16 images * 128 tiles of 32 pixels
  int b = blk >> 7, tile = blk & 127;
  int t = threadIdx.x;
  for (int idx = t; idx < NHEADS * CIN; idx += 256) {
    int n = idx >> 9, c = idx & 511;
    Pl[n * 516 + c] = P[((size_t)(b * NHEADS + n)) * CIN + c];
  }
  if (t < NHEADS) s0l[t] = s0[b * NHEADS + t];
  __syncthreads();
  int pl = t >> 3, n = t & 7;
  int pix = tile * 32 + pl;
  const uint4* xr = (const uint4*)(xb + ((size_t)b * PIX_PER_IMG + pix) * CIN);
  const float* Pr = Pl + n * 516;
  float acc = s0l[n];
  for (int cc = 0; cc < 64; ++cc) {
    uint4 u = xr[cc];
    int c = cc * 8;
    acc += b2f(u.x & 0xffff) * Pr[c + 0];
    acc += b2f(u.x >> 16) * Pr[c + 1];
    acc += b2f(u.y & 0xffff) * Pr[c + 2];
    acc += b2f(u.y >> 16) * Pr[c + 3];
    acc += b2f(u.z & 0xffff) * Pr[c + 4];
    acc += b2f(u.z >> 16) * Pr[c + 5];
    acc += b2f(u.w & 0xffff) * Pr[c + 6];
    acc += b2f(u.w >> 16) * Pr[c + 7];
  }
  s[((size_t)(b * NHEADS + n)) * PIX_PER_IMG + pix] = acc * 0.125f;
}

// ---------------- K5: row softmax -> ah ; col softmax -> avT ----------------
__global__ void k_softmax(const float* __restrict__ s,
                          float* __restrict__ ah, float* __restrict__ avT) {
  __shared__ float st[4096];
  int bn = blockIdx.x, t = threadIdx.x;
  const float* sp = s + (size_t)bn * 4096;
  for (int i = t; i < 4096; i += 256) st[i] = sp[i];
  __syncthreads();
  if (t < 64) {
    int h = t;
    float m = -1e30f;
    for (int w = 0; w < 64; ++w) m = fmaxf(m, st[h * 64 + w]);
    float sum = 0.f;
    for (int w = 0; w < 64; ++w) sum += __expf(st[h * 64 + w] - m);
    float inv = 1.f / sum;
    for (int w = 0; w < 64; ++w)
      ah[(size_t)bn * 4096 + h * 64 + w] = __expf(st[h * 64 + w] - m) * inv;
  } else if (t < 128) {
    int w = t - 64;
    float m = -1e30f;
    for (int h = 0; h < 64; ++h) m = fmaxf(m, st[h * 64 + w]);
    float sum = 0.f;
    for (int h = 0; h < 64; ++h) sum += __expf(st[h * 64 + w] - m);
    float inv = 1.f / sum;
    for (int h = 0; h < 64; ++h)
      avT[(size_t)bn * 4096 + w * 64 + h] = __expf(st[h * 64 + w] - m) * inv;
  }
}

// ---------------- K6a: xh[n][b*64+h][c] = sum_w ah[n,h,w]*x[b,h,w,c] --------
// XHV layout: [n][2048][512] bf16; rows 0..1023 = (b,h) for xh, 1024..2047 = (b,w) for xv
__global__ void k_xh(const unsigned short* __restrict__ xb,
                     const float* __restrict__ ahg,
                     unsigned short* __restrict__ XHV) {
  __shared__ unsigned short xs[64 * 256];   // [w][256 c] 32 KB
  __shared__ float ahl[NHEADS * 64];        // [n][w]
  int bh = blockIdx.x, ch = blockIdx.y, t = threadIdx.x;
  int b = bh >> 6, h = bh & 63;
  const unsigned short* src = xb + ((size_t)(b * PIX_PER_IMG + h * 64)) * CIN + ch * 256;
#pragma unroll
  for (int i = 0; i < 8; ++i) {
    int idx = i * 256 + t;                  // 2048 uint4
    int w = idx >> 5, off = idx & 31;
    ((uint4*)xs)[idx] = ((const uint4*)(src + (size_t)w * CIN))[off];
  }
#pragma unroll
  for (int i = 0; i < 2; ++i) {
    int idx = i * 256 + t;                  // 512 = 8n*64w
    ahl[idx] = ahg[((size_t)(b * NHEADS + (idx >> 6))) * PIX_PER_IMG + h * 64 + (idx & 63)];
  }
  __syncthreads();
  int n = t >> 5, oct = t & 31;
  float acc[8] = {0.f, 0.f, 0.f, 0.f, 0.f, 0.f, 0.f, 0.f};
  const float* ar = ahl + n * 64;
  for (int w = 0; w < 64; ++w) {
    float aw = ar[w];
    uint4 u = *(const uint4*)(xs + (size_t)w * 256 + oct * 8);
    acc[0] += aw * b2f(u.x & 0xffff);
    acc[1] += aw * b2f(u.x >> 16);
    acc[2] += aw * b2f(u.y & 0xffff);
    acc[3] += aw * b2f(u.y >> 16);
    acc[4] += aw * b2f(u.z & 0xffff);
    acc[5] += aw * b2f(u.z >> 16);
    acc[6] += aw * b2f(u.w & 0xffff);
    acc[7] += aw * b2f(u.w >> 16);
  }
  uint4 o;
  o.x = (unsigned)f2b(acc[0]) | ((unsigned)f2b(acc[1]) << 16);
  o.y = (unsigned)f2b(acc[2]) | ((unsigned)f2b(acc[3]) << 16);
  o.z = (unsigned)f2b(acc[4]) | ((unsigned)f2b(acc[5]) << 16);
  o.w = (unsigned)f2b(acc[6]) | ((unsigned)f2b(acc[7]) << 16);
  size_t dst = ((size_t)(n * 2048 + b * 64 + h)) * CIN + ch * 256 + oct * 8;
  *(uint4*)(XHV + dst) = o;
}

// ---------------- K6b: xv[n][b*64+w][c] = sum_h avT[n,w,h]*x[b,h,w,c] -------
__global__ void k_xv(const unsigned short* __restrict__ xb,
                     const float* __restrict__ avTg,
                     unsigned short* __restrict__ XHV) {
  __shared__ unsigned short xs[64 * 256];   // [h][256 c]
  __shared__ float avl[NHEADS * 64];        // [n][h]
  int bw = blockIdx.x, ch = blockIdx.y, t = threadIdx.x;
  int b = bw >> 6, w = bw & 63;
#pragma unroll
  for (int i = 0; i < 8; ++i) {
    int idx = i * 256 + t;
    int h = idx >> 5, off = idx & 31;
    ((uint4*)xs)[idx] =
        ((const uint4*)(xb + ((size_t)(b * PIX_PER_IMG + h * 64 + w)) * CIN + ch * 256))[off];
  }
#pragma unroll
  for (int i = 0; i < 2; ++i) {
    int idx = i * 256 + t;                  // 512 = 8n*64h
    avl[idx] = avTg[((size_t)(b * NHEADS + (idx >> 6))) * PIX_PER_IMG + w * 64 + (idx & 63)];
  }
  __syncthreads();
  int n = t >> 5, oct = t & 31;
  float acc[8] = {0.f, 0.f, 0.f, 0.f, 0.f, 0.f, 0.f, 0.f};
  const float* ar = avl + n * 64;
  for (int h = 0; h < 64; ++h) {
    float aw = ar[h];
    uint4 u = *(const uint4*)(xs + (size_t)h * 256 + oct * 8);
    acc[0] += aw * b2f(u.x & 0xffff);
    acc[1] += aw * b2f(u.x >> 16);
    acc[2] += aw * b2f(u.y & 0xffff);
    acc[3] += aw * b2f(u.y >> 16);
    acc[4] += aw * b2f(u.z & 0xffff);
    acc[5] += aw * b2f(u.z >> 16);
    acc[6] += aw * b2f(u.w & 0xffff);
    acc[7] += aw * b2f(u.w >> 16);
  }
  uint4 o;
  o.x = (unsigned)f2b(acc[0]) | ((unsigned)f2b(acc[1]) << 16);
  o.y = (unsigned)f2b(acc[2]) | ((unsigned)f2b(acc[3]) << 16);
  o.z = (unsigned)f2b(acc[4]) | ((unsigned)f2b(acc[5]) << 16);
  o.w = (unsigned)f2b(acc[6]) | ((unsigned)f2b(acc[7]) << 16);
  size_t dst = ((size_t)(n * 2048 + 1024 + b * 64 + w)) * CIN + ch * 256 + oct * 8;
  *(uint4*)(XHV + dst) = o;
}

// ---------------- K7: batched skinny GEMM: per head, [2048x512]@[512x64] ----
// A = XHV + head*2048*512, BT = WvT rows head*64..+64, out -> Ah / Av (fp32)
__global__ void k_gemm2(const unsigned short* __restrict__ XHV,
                        const unsigned short* __restrict__ WvT,
                        const float* __restrict__ bv,
                        float* __restrict__ Ah, float* __restrict__ Av) {
  __shared__ __align__(16) unsigned short As[128 * 64];   // 16 KB
  __shared__ __align__(16) unsigned short Bs[64 * 64];    // 8 KB
  const int t = threadIdx.x;
  const int wave = t >> 6, lane = t & 63;
  const int mtile = blockIdx.x, head = blockIdx.y;
  const int m0 = mtile * 128;
  const unsigned short* A = XHV + (size_t)head * 2048 * CIN;
  const unsigned short* BT = WvT + (size_t)head * 64 * CIN;

  f32x4 acc[2][4];
  for (int i = 0; i < 2; ++i)
    for (int j = 0; j < 4; ++j) acc[i][j] = (f32x4){0.f, 0.f, 0.f, 0.f};

  const int lrow = wave * 8 + (lane >> 3);   // per-issue row base
  const int lcolb = (lane & 7) * 16;

  for (int kt = 0; kt < 8; ++kt) {
    __syncthreads();
#pragma unroll
    for (int j = 0; j < 4; ++j) {
      gload_lds16((const char*)A + ((size_t)(m0 + j * 32 + lrow) * CIN + kt * 64) * 2 + lcolb,
                  (char*)As + (j * 32 + wave * 8) * 128);
    }
#pragma unroll
    for (int j = 0; j < 2; ++j) {
      gload_lds16((const char*)BT + ((size_t)(j * 32 + lrow) * CIN + kt * 64) * 2 + lcolb,
                  (char*)Bs + (j * 32 + wave * 8) * 128);
    }
    __syncthreads();
#pragma unroll
    for (int s = 0; s < 2; ++s) {
      bf16x8 af[2], bg[4];
#pragma unroll
      for (int i = 0; i < 2; ++i) {
        int mrow = wave * 32 + i * 16 + (lane & 15);
        af[i] = *(const bf16x8*)((const char*)As + mrow * 128 + s * 64 + ((lane >> 4) * 16));
      }
#pragma unroll
      for (int j = 0; j < 4; ++j) {
        int nrow = j * 16 + (lane & 15);
        bg[j] = *(const bf16x8*)((const char*)Bs + nrow * 128 + s * 64 + ((lane >> 4) * 16));
      }
#pragma unroll
      for (int i = 0; i < 2; ++i)
#pragma unroll
        for (int j = 0; j < 4; ++j)
          acc[i][j] = __builtin_amdgcn_mfma_f32_16x16x32_bf16(af[i], bg[j], acc[i][j], 0, 0, 0);
    }
  }
#pragma unroll
  for (int i = 0; i < 2; ++i)
#pragma unroll
    for (int j = 0; j < 4; ++j) {
      int v = j * 16 + (lane & 15);
      float bb = bv[head * 64 + v];
#pragma unroll
      for (int r = 0; r < 4; ++r) {
        int m = m0 + wave * 32 + i * 16 + ((lane >> 4) * 4) + r;   // 0..2047
        float val = acc[i][j][r] + bb;
        if (m < 1024) {
          int b = m >> 6, h = m & 63;
          Ah[((size_t)(b * NHEADS + head)) * 4096 + h * 64 + v] = val;
        } else {
          int m2 = m - 1024;
          int b = m2 >> 6, w = m2 & 63;
          Av[((size_t)(b * NHEADS + head)) * 4096 + w * 64 + v] = val;
        }
      }
    }
}

// ---------------- K8: a[pix,v] = sum_n A_h*A_v -> bf16 ----------------------
__global__ void k_combine(const float* __restrict__ Ah, const float* __restrict__ Av,
                          unsigned short* __restrict__ Af) {
  int t = threadIdx.x;
  int g = blockIdx.x * 4 + (t >> 6);
  int v = t & 63;
  int b = g >> 12;
  int rem = g & 4095;
  int h = rem >> 6, w = rem & 63;
  float a = 0.f;
#pragma unroll
  for (int n = 0; n < 8; ++n) {
    int bn = b * 8 + n;
    a += Ah[((size_t)bn * 64 + h) * 64 + v] * Av[((size_t)bn * 64 + w) * 64 + v];
  }
  Af[(size_t)g * 64 + v] = f2b(a);
}

extern "C" void kernel_launch(void* const* d_in, const int* in_sizes, int n_in,
                              void* d_out, int out_size, void* d_ws, size_t ws_size,
                              hipStream_t stream) {
  (void)in_sizes; (void)n_in; (void)out_size; (void)ws_size;
  const float* x = (const float*)d_in[0];
  const float* Wq = (const float*)d_in[1];
  const float* bq = (const float*)d_in[2];
  const float* Wk = (const float*)d_in[3];
  const float* bk = (const float*)d_in[4];
  const float* Wv = (const float*)d_in[5];
  const float* bv = (const float*)d_in[6];
  const float* Wo = (const float*)d_in[7];
  const float* bo = (const float*)d_in[8];
  float* out = (float*)d_out;

  char* ws = (char*)d_ws;
  unsigned short* xb = (unsigned short*)(ws + 0);            // 67,108,864
  float* s = (float*)(ws + 67108864);                        //  8,388,608
  float* partial = (float*)(ws + 75497472);                  //  2,097,152
  float* xbar = (float*)(ws + 77594624);                     //     32,768
  float* qbuf = (float*)(ws + 77627392);                     //     32,768
  float* P = (float*)(ws + 77660160);                        //    262,144
  float* s0 = (float*)(ws + 77922304);                       //        512
  float* attn_h = (float*)(ws + 77922816);                   //  2,097,152
  float* avT = (float*)(ws + 80019968);                      //  2,097,152
  unsigned short* XHV = (unsigned short*)(ws + 82117120);    // 16,777,216
  float* Ah = (float*)(ws + 98894336);                       //  2,097,152
  float* Av = (float*)(ws + 100991488);                      //  2,097,152
  unsigned short* Af = (unsigned short*)(ws + 103088640);    //  8,388,608
  unsigned short* WvT = (unsigned short*)(ws + 111477248);   //    524,288
  unsigned short* WoT = (unsigned short*)(ws + 112001536);   //     65,536
  // total ws use ~112 MB

  k_pool_convert<<<1024, 256, 0, stream>>>(x, xb, partial);
  k_xbar<<<32, 256, 0, stream>>>(partial, xbar);
  k_q<<<dim3(16, 8), 256, 0, stream>>>(xbar, Wq, bq, bk, qbuf, s0);
  k_p<<<dim3(8, 8), 256, 0, stream>>>(qbuf, Wk, P);
  k_prep_w<<<1152, 256, 0, stream>>>(Wv, Wo, WvT, WoT);
  k_scores<<<2048, 256, 0, stream>>>(xb, P, s0, s);
  k_softmax<<<128, 256, 0, stream>>>(s, attn_h, avT);
  k_xh<<<dim3(1024, 2), 256, 0, stream>>>(xb, attn_h, XHV);
  k_xv<<<dim3(1024, 2), 256, 0, stream>>>(xb, avT, XHV);
  k_gemm2<<<dim3(16, 8), 256, 0, stream>>>(XHV, WvT, bv, Ah, Av);
  k_combine<<<16384, 256, 0, stream>>>(Ah, Av, Af);
  k_gemm<1, false><<<dim3(4, 512), 256, 0, stream>>>(Af, WoT, bo, (void*)out);
}

// Round 3
// 371.727 us; speedup vs baseline: 1.3100x; 1.0112x over previous
//
#include <hip/hip_runtime.h>
#include <hip/hip_bf16.h>

#define NHEADS 8
#define DK 64
#define DV 64
#define CIN 512
#define PIX_PER_IMG 4096
#define NPIX 65536

typedef short bf16x8 __attribute__((ext_vector_type(8)));
typedef float f32x4 __attribute__((ext_vector_type(4)));

__device__ __forceinline__ float b2f(unsigned int u) {
  union { unsigned int i; float f; } v; v.i = u << 16; return v.f;
}
__device__ __forceinline__ unsigned short f2b(float f) {
  union { float f; unsigned int i; } v; v.f = f;
  unsigned int x = v.i;
  return (unsigned short)((x + 0x7fffu + ((x >> 16) & 1u)) >> 16);
}
__device__ __forceinline__ void gload_lds16(const void* g, void* l) {
  __builtin_amdgcn_global_load_lds(
      (const __attribute__((address_space(1))) void*)g,
      (__attribute__((address_space(3))) void*)l, 16, 0, 0);
}

// ---------------- K1: pooled sums (partial) + x -> bf16, vectorized ---------
// partial layout: [2048 chunks][512 c]  (2 half-chunks per 64-pixel block)
__global__ void k_pool_convert(const float* __restrict__ x,
                               unsigned short* __restrict__ xb,
                               float* __restrict__ partial) {
  int blk = blockIdx.x;             // 1024 = 16 images * 64 chunks of 64 pixels
  int b = blk >> 6, chunk = blk & 63;
  int t = threadIdx.x;              // 256
  int c4 = t & 127;                 // float4 index within row (512 c = 128 f4)
  int half = t >> 7;                // pixel parity
  size_t rowbase = (size_t)b * PIX_PER_IMG + chunk * 64;
  const float4* x4 = (const float4*)x;
  float4 acc = make_float4(0.f, 0.f, 0.f, 0.f);
#pragma unroll 4
  for (int i = 0; i < 32; ++i) {
    int p = 2 * i + half;
    float4 v = x4[(rowbase + p) * 128 + c4];
    acc.x += v.x; acc.y += v.y; acc.z += v.z; acc.w += v.w;
    uint2 o;
    o.x = (unsigned)f2b(v.x) | ((unsigned)f2b(v.y) << 16);
    o.y = (unsigned)f2b(v.z) | ((unsigned)f2b(v.w) << 16);
    *(uint2*)(xb + (rowbase + p) * CIN + c4 * 4) = o;
  }
  *(float4*)(partial + ((size_t)(blk * 2 + half)) * CIN + c4 * 4) = acc;
}

// ---------------- K2: xbar -> q -> s0, P  (one block per (b,n)) -------------
__global__ void k_qp2(const float* __restrict__ partial,
                      const float* __restrict__ Wq, const float* __restrict__ bq,
                      const float* __restrict__ Wk, const float* __restrict__ bk,
                      float* __restrict__ P, float* __restrict__ s0) {
  __shared__ float xs[CIN];
  __shared__ float red[256];
  __shared__ float qsh[64];
  int b = blockIdx.x, n = blockIdx.y, t = threadIdx.x;
  for (int c = t; c < CIN; c += 256) {
    float s = 0.f;
    for (int ch = 0; ch < 128; ++ch) s += partial[((size_t)(b * 128 + ch)) * CIN + c];
    xs[c] = s * (1.0f / 4096.0f);
  }
  __syncthreads();
  int jj = t & 63, part = t >> 6;
  {
    float acc = 0.f;
    const float* wp = Wq + (size_t)(part * 128) * CIN + n * 64 + jj;
    for (int ci = 0; ci < 128; ++ci)
      acc += xs[part * 128 + ci] * wp[(size_t)ci * CIN];
    red[t] = acc;
  }
  __syncthreads();
  if (t < 64)
    qsh[t] = red[t] + red[t + 64] + red[t + 128] + red[t + 192] + bq[n * 64 + t];
  __syncthreads();
  if (t == 0) {
    float s = 0.f;
    for (int k = 0; k < 64; ++k) s += qsh[k] * bk[n * 64 + k];
    s0[b * NHEADS + n] = s;
  }
  for (int c = t; c < CIN; c += 256) {
    float acc = 0.f;
    const float* wr = Wk + (size_t)c * CIN + n * 64;
    for (int k = 0; k < 64; ++k) acc += qsh[k] * wr[k];
    P[((size_t)(b * NHEADS + n)) * CIN + c] = acc;
  }
}

// ---------------- K3: weight transposes -> bf16 -----------------------------
__global__ void k_prep_w(const float* __restrict__ Wv, const float* __restrict__ Wo,
                         unsigned short* __restrict__ WvT, unsigned short* __restrict__ WoT) {
  int idx = blockIdx.x * 256 + threadIdx.x;   // grid 1152 -> 294912
  if (idx < 262144) {
    int n = idx >> 9, c = idx & 511;          // WvT[n][c] = Wv[c][n]
    WvT[idx] = f2b(Wv[(size_t)c * 512 + n]);
  } else {
    int j = idx - 262144;                      // 32768: WoT[o][k] = Wo[k][o]
    int o = j >> 6, kk = j & 63;
    WoT[j] = f2b(Wo[(size_t)kk * 512 + o]);
  }
}

// ---------------- K4: scores s[b,n,pix] = scale*(x.P + s0) ------------------
__global__ void k_scores(const unsigned short* __restrict__ xb,
                         const float* __restrict__ P, const float* __restrict__ s0,
                         float* __restrict__ s) {
  __shared__ float Pl[NHEADS * 516];
  __shared__ float s0l[NHEADS];
  int blk = blockIdx.x;   // 2048 = 16 images * 128 tiles of 32 pixels
  int b = blk >> 7, tile = blk & 127;
  int t = threadIdx.x;
  for (int idx = t; idx < NHEADS * CIN; idx += 256) {
    int n = idx >> 9, c = idx & 511;
    Pl[n * 516 + c] = P[((size_t)(b * NHEADS + n)) * CIN + c];
  }
  if (t < NHEADS) s0l[t] = s0[b * NHEADS + t];
  __syncthreads();
  int pl = t >> 3, n = t & 7;
  int pix = tile * 32 + pl;
  const uint4* xr = (const uint4*)(xb + ((size_t)b * PIX_PER_IMG + pix) * CIN);
  const float* Pr = Pl + n * 516;
  float acc = s0l[n];
  for (int cc = 0; cc < 64; ++cc) {
    uint4 u = xr[cc];
    int c = cc * 8;
    acc += b2f(u.x & 0xffff) * Pr[c + 0];
    acc += b2f(u.x >> 16) * Pr[c + 1];
    acc += b2f(u.y & 0xffff) * Pr[c + 2];
    acc += b2f(u.y >> 16) * Pr[c + 3];
    acc += b2f(u.z & 0xffff) * Pr[c + 4];
    acc += b2f(u.z >> 16) * Pr[c + 5];
    acc += b2f(u.w & 0xffff) * Pr[c + 6];
    acc += b2f(u.w >> 16) * Pr[c + 7];
  }
  s[((size_t)(b * NHEADS + n)) * PIX_PER_IMG + pix] = acc * 0.125f;
}

// ---------------- K5: row softmax -> ah ; col softmax -> avT ----------------
__global__ void k_softmax(const float* __restrict__ s,
                          float* __restrict__ ah, float* __restrict__ avT) {
  __shared__ float st[4096];
  int bn = blockIdx.x, t = threadIdx.x;
  const float* sp = s + (size_t)bn * 4096;
  for (int i = t; i < 4096; i += 256) st[i] = sp[i];
  __syncthreads();
  if (t < 64) {
    int h = t;
    float m = -1e30f;
    for (int w = 0; w < 64; ++w) m = fmaxf(m, st[h * 64 + w]);
    float sum = 0.f;
    for (int w = 0; w < 64; ++w) sum += __expf(st[h * 64 + w] - m);
    float inv = 1.f / sum;
    for (int w = 0; w < 64; ++w)
      ah[(size_t)bn * 4096 + h * 64 + w] = __expf(st[h * 64 + w] - m) * inv;
  } else if (t < 128) {
    int w = t - 64;
    float m = -1e30f;
    for (int h = 0; h < 64; ++h) m = fmaxf(m, st[h * 64 + w]);
    float sum = 0.f;
    for (int h = 0; h < 64; ++h) sum += __expf(st[h * 64 + w] - m);
    float inv = 1.f / sum;
    for (int h = 0; h < 64; ++h)
      avT[(size_t)bn * 4096 + w * 64 + h] = __expf(st[h * 64 + w] - m) * inv;
  }
}

// ---------------- K6a: xh[n][b*64+h][c] = sum_w ah[n,h,w]*x[b,h,w,c] --------
// XHV layout: [n][2048][512] bf16; rows 0..1023 = (b,h) xh, 1024..2047 = (b,w) xv
__global__ void k_xh(const unsigned short* __restrict__ xb,
                     const float* __restrict__ ahg,
                     unsigned short* __restrict__ XHV) {
  __shared__ unsigned short xs[64 * 256];   // [w][256 c] 32 KB
  __shared__ float ahl[NHEADS * 64];        // [n][w]
  int bh = blockIdx.x, ch = blockIdx.y, t = threadIdx.x;
  int b = bh >> 6, h = bh & 63;
  const unsigned short* src = xb + ((size_t)(b * PIX_PER_IMG + h * 64)) * CIN + ch * 256;
#pragma unroll
  for (int i = 0; i < 8; ++i) {
    int idx = i * 256 + t;                  // 2048 uint4
    int w = idx >> 5, off = idx & 31;
    ((uint4*)xs)[idx] = ((const uint4*)(src + (size_t)w * CIN))[off];
  }
#pragma unroll
  for (int i = 0; i < 2; ++i) {
    int idx = i * 256 + t;                  // 512 = 8n*64w
    ahl[idx] = ahg[((size_t)(b * NHEADS + (idx >> 6))) * PIX_PER_IMG + h * 64 + (idx & 63)];
  }
  __syncthreads();
  int n = t >> 5, oct = t & 31;
  float acc[8] = {0.f, 0.f, 0.f, 0.f, 0.f, 0.f, 0.f, 0.f};
  const float* ar = ahl + n * 64;
  for (int w = 0; w < 64; ++w) {
    float aw = ar[w];
    uint4 u = *(const uint4*)(xs + (size_t)w * 256 + oct * 8);
    acc[0] += aw * b2f(u.x & 0xffff);
    acc[1] += aw * b2f(u.x >> 16);
    acc[2] += aw * b2f(u.y & 0xffff);
    acc[3] += aw * b2f(u.y >> 16);
    acc[4] += aw * b2f(u.z & 0xffff);
    acc[5] += aw * b2f(u.z >> 16);
    acc[6] += aw * b2f(u.w & 0xffff);
    acc[7] += aw * b2f(u.w >> 16);
  }
  uint4 o;
  o.x = (unsigned)f2b(acc[0]) | ((unsigned)f2b(acc[1]) << 16);
  o.y = (unsigned)f2b(acc[2]) | ((unsigned)f2b(acc[3]) << 16);
  o.z = (unsigned)f2b(acc[4]) | ((unsigned)f2b(acc[5]) << 16);
  o.w = (unsigned)f2b(acc[6]) | ((unsigned)f2b(acc[7]) << 16);
  size_t dst = ((size_t)(n * 2048 + b * 64 + h)) * CIN + ch * 256 + oct * 8;
  *(uint4*)(XHV + dst) = o;
}

// ---------------- K6b: xv[n][b*64+w][c] = sum_h avT[n,w,h]*x[b,h,w,c] -------
__global__ void k_xv(const unsigned short* __restrict__ xb,
                     const float* __restrict__ avTg,
                     unsigned short* __restrict__ XHV) {
  __shared__ unsigned short xs[64 * 256];   // [h][256 c]
  __shared__ float avl[NHEADS * 64];        // [n][h]
  int bw = blockIdx.x, ch = blockIdx.y, t = threadIdx.x;
  int b = bw >> 6, w = bw & 63;
#pragma unroll
  for (int i = 0; i < 8; ++i) {
    int idx = i * 256 + t;
    int h = idx >> 5, off = idx & 31;
    ((uint4*)xs)[idx] =
        ((const uint4*)(xb + ((size_t)(b * PIX_PER_IMG + h * 64 + w)) * CIN + ch * 256))[off];
  }
#pragma unroll
  for (int i = 0; i < 2; ++i) {
    int idx = i * 256 + t;                  // 512 = 8n*64h
    avl[idx] = avTg[((size_t)(b * NHEADS + (idx >> 6))) * PIX_PER_IMG + w * 64 + (idx & 63)];
  }
  __syncthreads();
  int n = t >> 5, oct = t & 31;
  float acc[8] = {0.f, 0.f, 0.f, 0.f, 0.f, 0.f, 0.f, 0.f};
  const float* ar = avl + n * 64;
  for (int h = 0; h < 64; ++h) {
    float aw = ar[h];
    uint4 u = *(const uint4*)(xs + (size_t)h * 256 + oct * 8);
    acc[0] += aw * b2f(u.x & 0xffff);
    acc[1] += aw * b2f(u.x >> 16);
    acc[2] += aw * b2f(u.y & 0xffff);
    acc[3] += aw * b2f(u.y >> 16);
    acc[4] += aw * b2f(u.z & 0xffff);
    acc[5] += aw * b2f(u.z >> 16);
    acc[6] += aw * b2f(u.w & 0xffff);
    acc[7] += aw * b2f(u.w >> 16);
  }
  uint4 o;
  o.x = (unsigned)f2b(acc[0]) | ((unsigned)f2b(acc[1]) << 16);
  o.y = (unsigned)f2b(acc[2]) | ((unsigned)f2b(acc[3]) << 16);
  o.z = (unsigned)f2b(acc[4]) | ((unsigned)f2b(acc[5]) << 16);
  o.w = (unsigned)f2b(acc[6]) | ((unsigned)f2b(acc[7]) << 16);
  size_t dst = ((size_t)(n * 2048 + 1024 + b * 64 + w)) * CIN + ch * 256 + oct * 8;
  *(uint4*)(XHV + dst) = o;
}

// ---------------- K7: batched skinny GEMM: per head, [2048x512]@[512x64] ----
__global__ void k_gemm2(const unsigned short* __restrict__ XHV,
                        const unsigned short* __restrict__ WvT,
                        const float* __restrict__ bv,
                        float* __restrict__ Ah, float* __restrict__ Av) {
  __shared__ __align__(16) unsigned short As[128 * 64];   // 16 KB
  __shared__ __align__(16) unsigned short Bs[64 * 64];    // 8 KB
  const int t = threadIdx.x;
  const int wave = t >> 6, lane = t & 63;
  const int mtile = blockIdx.x, head = blockIdx.y;
  const int m0 = mtile * 128;
  const unsigned short* A = XHV + (size_t)head * 2048 * CIN;
  const unsigned short* BT = WvT + (size_t)head * 64 * CIN;

  f32x4 acc[2][4];
  for (int i = 0; i < 2; ++i)
    for (int j = 0; j < 4; ++j) acc[i][j] = (f32x4){0.f, 0.f, 0.f, 0.f};

  const int lrow = wave * 8 + (lane >> 3);
  const int lcolb = (lane & 7) * 16;

  for (int kt = 0; kt < 8; ++kt) {
    __syncthreads();
#pragma unroll
    for (int j = 0; j < 4; ++j) {
      gload_lds16((const char*)A + ((size_t)(m0 + j * 32 + lrow) * CIN + kt * 64) * 2 + lcolb,
                  (char*)As + (j * 32 + wave * 8) * 128);
    }
#pragma unroll
    for (int j = 0; j < 2; ++j) {
      gload_lds16((const char*)BT + ((size_t)(j * 32 + lrow) * CIN + kt * 64) * 2 + lcolb,
                  (char*)Bs + (j * 32 + wave * 8) * 128);
    }
    __syncthreads();
#pragma unroll
    for (int s = 0; s < 2; ++s) {
      bf16x8 af[2], bg[4];
#pragma unroll
      for (int i = 0; i < 2; ++i) {
        int mrow = wave * 32 + i * 16 + (lane & 15);
        af[i] = *(const bf16x8*)((const char*)As + mrow * 128 + s * 64 + ((lane >> 4) * 16));
      }
#pragma unroll
      for (int j = 0; j < 4; ++j) {
        int nrow = j * 16 + (lane & 15);
        bg[j] = *(const bf16x8*)((const char*)Bs + nrow * 128 + s * 64 + ((lane >> 4) * 16));
      }
#pragma unroll
      for (int i = 0; i < 2; ++i)
#pragma unroll
        for (int j = 0; j < 4; ++j)
          acc[i][j] = __builtin_amdgcn_mfma_f32_16x16x32_bf16(af[i], bg[j], acc[i][j], 0, 0, 0);
    }
  }
#pragma unroll
  for (int i = 0; i < 2; ++i)
#pragma unroll
    for (int j = 0; j < 4; ++j) {
      int v = j * 16 + (lane & 15);
      float bb = bv[head * 64 + v];
#pragma unroll
      for (int r = 0; r < 4; ++r) {
        int m = m0 + wave * 32 + i * 16 + ((lane >> 4) * 4) + r;   // 0..2047
        float val = acc[i][j][r] + bb;
        if (m < 1024) {
          int b = m >> 6, h = m & 63;
          Ah[((size_t)(b * NHEADS + head)) * 4096 + h * 64 + v] = val;
        } else {
          int m2 = m - 1024;
          int b = m2 >> 6, w = m2 & 63;
          Av[((size_t)(b * NHEADS + head)) * 4096 + w * 64 + v] = val;
        }
      }
    }
}

// ---------------- K8: fused combine + out-GEMM ------------------------------
// A-tile (128 pix x 64 v) computed from Ah/Av in-kernel, B = WoT, out fp32.
__global__ void k_outgemm(const float* __restrict__ Ah, const float* __restrict__ Av,
                          const unsigned short* __restrict__ WoT,
                          const float* __restrict__ bo, float* __restrict__ out) {
  __shared__ __align__(16) unsigned short As[128 * 64];
  __shared__ __align__(16) unsigned short Bs[128 * 64];
  const int t = threadIdx.x;
  const int wave = t >> 6, lane = t & 63;
  const int wr = wave >> 1, wc = wave & 1;
  const int m0 = blockIdx.y * 128, n0 = blockIdx.x * 128;
  const int b = m0 >> 12, h0 = (m0 >> 6) & 63;   // tile spans h0, h0+1; w 0..63

  // stage Bs: WoT rows n0..n0+127, 64 k (128 B/row)
  const int srow = wave * 32 + (lane >> 3), scolb = (lane & 7) * 16;
#pragma unroll
  for (int j = 0; j < 4; ++j)
    gload_lds16((const char*)WoT + ((size_t)(n0 + srow + j * 8) * 64) * 2 + scolb,
                (char*)Bs + wave * 4096 + j * 1024);

  // compute As[r][v] = sum_n Ah[b,n,h(r),v] * Av[b,n,w(r),v], r = hh*64+w
  {
    const int v = t & 63, rg = t >> 6;
    float ahv0[8], ahv1[8];
#pragma unroll
    for (int n = 0; n < 8; ++n) {
      ahv0[n] = Ah[((size_t)((b * 8 + n) * 64 + h0)) * 64 + v];
      ahv1[n] = Ah[((size_t)((b * 8 + n) * 64 + h0 + 1)) * 64 + v];
    }
#pragma unroll 2
    for (int i = 0; i < 16; ++i) {
      int w = rg * 16 + i;
      float a0 = 0.f, a1 = 0.f;
#pragma unroll
      for (int n = 0; n < 8; ++n) {
        float av = Av[((size_t)((b * 8 + n) * 64 + w)) * 64 + v];
        a0 += ahv0[n] * av;
        a1 += ahv1[n] * av;
      }
      As[w * 64 + v] = f2b(a0);
      As[(64 + w) * 64 + v] = f2b(a1);
    }
  }
  __syncthreads();

  f32x4 acc[4][4];
  for (int i = 0; i < 4; ++i)
    for (int j = 0; j < 4; ++j) acc[i][j] = (f32x4){0.f, 0.f, 0.f, 0.f};
#pragma unroll
  for (int s = 0; s < 2; ++s) {
    bf16x8 af[4], bg[4];
#pragma unroll
    for (int i = 0; i < 4; ++i) {
      int mrow = wr * 64 + i * 16 + (lane & 15);
      af[i] = *(const bf16x8*)((const char*)As + mrow * 128 + s * 64 + ((lane >> 4) * 16));
    }
#pragma unroll
    for (int j = 0; j < 4; ++j) {
      int nrow = wc * 64 + j * 16 + (lane & 15);
      bg[j] = *(const bf16x8*)((const char*)Bs + nrow * 128 + s * 64 + ((lane >> 4) * 16));
    }
#pragma unroll
    for (int i = 0; i < 4; ++i)
#pragma unroll
      for (int j = 0; j < 4; ++j)
        acc[i][j] = __builtin_amdgcn_mfma_f32_16x16x32_bf16(af[i], bg[j], acc[i][j], 0, 0, 0);
  }
#pragma unroll
  for (int i = 0; i < 4; ++i)
#pragma unroll
    for (int j = 0; j < 4; ++j) {
      int mbase = m0 + wr * 64 + i * 16 + ((lane >> 4) * 4);
      int n = n0 + wc * 64 + j * 16 + (lane & 15);
      float bb = bo[n];
#pragma unroll
      for (int r = 0; r < 4; ++r)
        out[(size_t)(mbase + r) * 512 + n] = acc[i][j][r] + bb;
    }
}

extern "C" void kernel_launch(void* const* d_in, const int* in_sizes, int n_in,
                              void* d_out, int out_size, void* d_ws, size_t ws_size,
                              hipStream_t stream) {
  (void)in_sizes; (void)n_in; (void)out_size; (void)ws_size;
  const float* x = (const float*)d_in[0];
  const float* Wq = (const float*)d_in[1];
  const float* bq = (const float*)d_in[2];
  const float* Wk = (const float*)d_in[3];
  const float* bk = (const float*)d_in[4];
  const float* Wv = (const float*)d_in[5];
  const float* bv = (const float*)d_in[6];
  const float* Wo = (const float*)d_in[7];
  const float* bo = (const float*)d_in[8];
  float* out = (float*)d_out;

  char* ws = (char*)d_ws;
  unsigned short* xb = (unsigned short*)(ws + 0);            // 67,108,864
  float* s = (float*)(ws + 67108864);                        //  2,097,152
  float* partial = (float*)(ws + 69206016);                  //  4,194,304
  float* P = (float*)(ws + 73400320);                        //    262,144
  float* s0 = (float*)(ws + 73662464);                       //        512
  float* attn_h = (float*)(ws + 73662976);                   //  2,097,152
  float* avT = (float*)(ws + 75760128);                      //  2,097,152
  unsigned short* XHV = (unsigned short*)(ws + 77857280);    // 16,777,216
  float* Ah = (float*)(ws + 94634496);                       //  2,097,152
  float* Av = (float*)(ws + 96731648);                       //  2,097,152
  unsigned short* WvT = (unsigned short*)(ws + 98828800);    //    524,288
  unsigned short* WoT = (unsigned short*)(ws + 99353088);    //     65,536
  // total ws use ~99.4 MB

  k_pool_convert<<<1024, 256, 0, stream>>>(x, xb, partial);
  k_qp2<<<dim3(16, 8), 256, 0, stream>>>(partial, Wq, bq, Wk, bk, P, s0);
  k_prep_w<<<1152, 256, 0, stream>>>(Wv, Wo, WvT, WoT);
  k_scores<<<2048, 256, 0, stream>>>(xb, P, s0, s);
  k_softmax<<<128, 256, 0, stream>>>(s, attn_h, avT);
  k_xh<<<dim3(1024, 2), 256, 0, stream>>>(xb, attn_h, XHV);
  k_xv<<<dim3(1024, 2), 256, 0, stream>>>(xb, avT, XHV);
  k_gemm2<<<dim3(16, 8), 256, 0, stream>>>(XHV, WvT, bv, Ah, Av);
  k_outgemm<<<dim3(4, 512), 256, 0, stream>>>(Ah, Av, WoT, bo, out);
}